// Round 4
// baseline (242.259 us; speedup 1.0000x reference)
//
#include <hip/hip_runtime.h>

constexpr int FRAME_LEN = 130;   // floats per frame
constexpr int HALF      = 65;    // floats per hand block
constexpr int BLOCK     = 256;   // threads per block
constexpr int FPB       = 32;    // frames per block
constexpr int CHUNK_F   = FPB * FRAME_LEN;   // 4160 floats
constexpr int CHUNK_V4  = CHUNK_F / 4;       // 1040 vec4 = 4*256 + 16

typedef float v4f __attribute__((ext_vector_type(4)));

// frame = idx / 130 for idx < 7825 via magic multiply
__device__ __forceinline__ int div130(int idx) {
    return (int)(((unsigned)idx * 8067u) >> 20);
}

__device__ __forceinline__ bool skip_pred(float h0, float p0, float h1, float p1) {
    const bool nan0 = (h0 != h0);
    const bool nan1 = (h1 != h1);
    const bool no_nan = !nan0 && !nan1;
    const bool eq = (h0 == h1);
    return (h1 > h0) ||
           (nan0 && nan1) ||
           (nan0 && (h1 == 1.0f)) ||
           (nan1 && (h0 == 0.0f)) ||
           (no_nan && eq && (h0 == 0.0f) && (p0 > p1)) ||
           (no_nan && eq && (h0 == 1.0f) && (p0 < p1));
}

// One output vec4 of the block-local chunk.
// out[j] = X[fl*130 + ((jj + (skip?0:65)) mod 130)]; 65 == 1 (mod 4), so a
// non-boundary out-vec4 is a funnel shift r = s&3 in {0,1,3} of two ALIGNED
// input vec4s va = Xv[s>>2], vb = Xv[s>>2 + 1].
__device__ __forceinline__ v4f make_out(const v4f* __restrict__ Xv,
                                        const float* __restrict__ Xb,
                                        unsigned mask, int i) {
    const int idx = 4 * i;
    const int fl  = div130(idx);
    const int jj  = idx - fl * FRAME_LEN;
    const bool fast = (jj <= FRAME_LEN - 4) && (jj < HALF - 3 || jj >= HALF);
    v4f r;
    if (fast) {
        const bool skipf = (mask >> fl) & 1u;
        const bool lo = (jj < HALF);
        const int s = idx + (skipf ? 0 : (lo ? HALF : -HALF));
        const int a = s >> 2;
        int a1 = a + 1;                       // clamp: only unused (skip) case
        if (a1 >= CHUNK_V4) a1 = CHUNK_V4 - 1; // can reach chunk end
        const v4f va = Xv[a];
        const v4f vb = Xv[a1];
        v4f f1; f1.x = va.y; f1.y = va.z; f1.z = va.w; f1.w = vb.x;   // r==1
        v4f f3; f3.x = va.w; f3.y = vb.x; f3.z = vb.y; f3.w = vb.z;   // r==3
        const v4f swp = lo ? f1 : f3;
        r = skipf ? va : swp;                 // r==0 (skip) is va itself
    } else {
        // frame-boundary or half-boundary straddling vec4 (~3%)
#pragma unroll
        for (int e = 0; e < 4; ++e) {
            const int ide = idx + e;
            const int fle = div130(ide);
            const int je  = ide - fle * FRAME_LEN;
            const bool sk = (mask >> fle) & 1u;
            int sj = je + (sk ? 0 : (je < HALF ? HALF : -HALF));
            ((float*)&r)[e] = Xb[fle * FRAME_LEN + sj];
        }
    }
    return r;
}

__global__ __launch_bounds__(BLOCK, 4)
void hand_sorter_kernel(const float* __restrict__ X, float* __restrict__ out,
                        int n_frames) {
    const int t = threadIdx.x;
    const long long frame0 = (long long)blockIdx.x * FPB;
    const long long rem = (long long)n_frames - frame0;
    const int frames_here = rem < (long long)FPB ? (int)rem : FPB;
    const long long base = frame0 * (long long)FRAME_LEN;
    const float* __restrict__ Xb = X + base;
    float* __restrict__ Ob = out + base;

    if (frames_here == FPB) {
        // ---- per-wave skip mask: lanes 0..31 test frame==lane, no LDS/barrier
        const int lane = t & 63;
        bool pred = false;
        if (lane < FPB) {
            const float* fr = Xb + lane * FRAME_LEN;
            const float2 a = *(const float2*)fr;          // h0, p0
            const float2 b = *(const float2*)(fr + 64);   // -, h1
            const float2 c = *(const float2*)(fr + 66);   // p1, -
            pred = skip_pred(a.x, a.y, b.y, c.x);
        }
        const unsigned mask = (unsigned)__ballot(pred);

        const v4f* __restrict__ Xv = (const v4f*)Xb;
        v4f* __restrict__ Ov = (v4f*)Ob;

        // ---- 4(+1) outputs per thread, fully unrolled, no barriers ----
        v4f o0 = make_out(Xv, Xb, mask, t);
        v4f o1 = make_out(Xv, Xb, mask, t + 256);
        v4f o2 = make_out(Xv, Xb, mask, t + 512);
        v4f o3 = make_out(Xv, Xb, mask, t + 768);
        __builtin_nontemporal_store(o0, Ov + t);
        __builtin_nontemporal_store(o1, Ov + t + 256);
        __builtin_nontemporal_store(o2, Ov + t + 512);
        __builtin_nontemporal_store(o3, Ov + t + 768);
        if (t < CHUNK_V4 - 1024) {
            v4f o4 = make_out(Xv, Xb, mask, t + 1024);
            __builtin_nontemporal_store(o4, Ov + t + 1024);
        }
    } else {
        // ---- generic tail path (never taken for bench shape) ----
        const int nf = frames_here * FRAME_LEN;
        for (int i = t; i < nf; i += BLOCK) {
            const int fle = div130(i);
            const int je  = i - fle * FRAME_LEN;
            const float* fr = Xb + fle * FRAME_LEN;
            const bool sk = skip_pred(fr[0], fr[1], fr[HALF], fr[HALF + 1]);
            int sj = je + (sk ? 0 : (je < HALF ? HALF : -HALF));
            Ob[i] = fr[sj];
        }
    }
}

extern "C" void kernel_launch(void* const* d_in, const int* in_sizes, int n_in,
                              void* d_out, int out_size, void* d_ws, size_t ws_size,
                              hipStream_t stream) {
    const float* X = (const float*)d_in[0];
    float* out = (float*)d_out;
    const int n_frames = in_sizes[0] / FRAME_LEN;   // 262144
    const int n_blocks = (n_frames + FPB - 1) / FPB;
    hand_sorter_kernel<<<n_blocks, BLOCK, 0, stream>>>(X, out, n_frames);
}